// Round 4
// baseline (267.193 us; speedup 1.0000x reference)
//
#include <hip/hip_runtime.h>

#define NB 16
#define HH 512
#define WW 512
#define HWN (HH * WW)            // 262144 = 1<<18
#define SENT HWN                  // background sentinel
#define KC 512                    // max regions kept per image
#define RCAP 4096                 // root list capacity per image
#define CCAP 8192                 // tile-root candidate capacity per image
#define PN (NB * HWN)
#define TPB 256
#define IMAX 0x7FFFFFFF
#define TS 64                     // CCL tile side
#define TSQ (TS * TS)             // 4096, local sentinel

// ---------------- union-find helpers (global mem) ----------------
__device__ __forceinline__ int findRoot(int* L, int i) {
    int p = L[i];
    while (p != i) { i = p; p = L[i]; }
    return i;
}

__device__ __forceinline__ int chaseRoot(const int* __restrict__ L, int i) {
    int p = L[i];
    while (p != i) { i = p; p = L[i]; }
    return i;
}

__device__ __forceinline__ void unite(int* L, int a, int b) {
    int ra = findRoot(L, a);
    int rb = findRoot(L, b);
    while (ra != rb) {
        int lo = min(ra, rb), hi = max(ra, rb);
        int old = atomicMin(&L[hi], lo);
        if (old == hi) return;
        ra = old; rb = lo;
    }
}

// ---------------- union-find helpers (LDS) ----------------
__device__ __forceinline__ int findRootL(int* s, int i) {
    int p = s[i];
    while (p != i) { i = p; p = s[i]; }
    return i;
}

__device__ __forceinline__ void uniteL(int* s, int a, int b) {
    int ra = findRootL(s, a);
    int rb = findRootL(s, b);
    while (ra != rb) {
        int lo = min(ra, rb), hi = max(ra, rb);
        int old = atomicMin(&s[hi], lo);
        if (old == hi) return;
        ra = old; rb = lo;
    }
}

// binary search exact key in ascending array of KC ints (padded IMAX)
__device__ __forceinline__ int bsearch_k(const int* a, int key) {
    int lo = 0, hi = KC;
    while (lo < hi) { int m = (lo + hi) >> 1; if (a[m] < key) lo = m + 1; else hi = m; }
    return (lo < KC && a[lo] == key) ? lo : -1;
}

// ---------------- kernels ----------------
// Per-tile CCL: run-based labels (ballot), reduced union rules, all in LDS.
// Also appends tile-root pixels to the per-image root-candidate list.
__global__ __launch_bounds__(TPB) void k_local(const float* __restrict__ in, const float* __restrict__ tg,
                        int* __restrict__ labP, int* __restrict__ labG,
                        int* __restrict__ candP, int* __restrict__ candG,
                        int* __restrict__ candCntP, int* __restrict__ candCntG) {
    __shared__ int sp[TSQ];
    __shared__ int sg[TSQ];
    __shared__ unsigned long long rmP[TS], rmG[TS];
    int b = blockIdx.x >> 6;            // 64 tiles per image (8x8)
    int tile = blockIdx.x & 63;
    int r0 = (tile >> 3) << 6, c0 = (tile & 7) << 6;
    int base = (b << 18) + (r0 << 9) + c0;
    int wv = threadIdx.x >> 6, lane = threadIdx.x & 63;

    // phase 1: batched loads, ballot row masks, run-start labels (no atomics)
    float vin[16], vtg[16];
    #pragma unroll
    for (int k = 0; k < 16; k++) {
        int lr = wv + (k << 2);
        vin[k] = in[base + (lr << 9) + lane];
        vtg[k] = tg[base + (lr << 9) + lane];
    }
    #pragma unroll
    for (int k = 0; k < 16; k++) {
        int lr = wv + (k << 2);
        bool p = vin[k] > 0.0f;         // sigmoid(x)>0.5 <=> x>0
        bool q = vtg[k] > 0.5f;
        unsigned long long mp = __ballot(p);
        unsigned long long mq = __ballot(q);
        int t = (lr << 6) + lane;
        unsigned long long below = (lane == 0) ? 0ULL : ((~mp) & ((1ULL << lane) - 1ULL));
        int st = below ? (64 - __clzll(below)) : 0;
        sp[t] = p ? ((lr << 6) + st) : TSQ;
        below = (lane == 0) ? 0ULL : ((~mq) & ((1ULL << lane) - 1ULL));
        st = below ? (64 - __clzll(below)) : 0;
        sg[t] = q ? ((lr << 6) + st) : TSQ;
        if (lane == 0) { rmP[lr] = mp; rmG[lr] = mq; }
    }
    __syncthreads();

    // phase 2: inter-row unions, reduced rules (one union per adjacent run-pair)
    for (int lr = wv; lr < TS; lr += 4) {
        if (lr == 0) continue;
        int t = (lr << 6) + lane;
        {
            unsigned long long m = rmP[lr], a = rmP[lr - 1];
            if ((m >> lane) & 1ULL) {
                bool N  = (a >> lane) & 1ULL;
                bool W  = lane > 0  && ((m >> (lane - 1)) & 1ULL);
                bool NW = lane > 0  && ((a >> (lane - 1)) & 1ULL);
                bool E  = lane < 63 && ((m >> (lane + 1)) & 1ULL);
                bool NE = lane < 63 && ((a >> (lane + 1)) & 1ULL);
                if (N) { if (!(W && NW)) uniteL(sp, t, t - TS); }
                else {
                    if (NW && !W) uniteL(sp, t, t - TS - 1);
                    if (NE && !E) uniteL(sp, t, t - TS + 1);
                }
            }
        }
        {
            unsigned long long m = rmG[lr], a = rmG[lr - 1];
            if ((m >> lane) & 1ULL) {
                bool N  = (a >> lane) & 1ULL;
                bool W  = lane > 0  && ((m >> (lane - 1)) & 1ULL);
                bool NW = lane > 0  && ((a >> (lane - 1)) & 1ULL);
                bool E  = lane < 63 && ((m >> (lane + 1)) & 1ULL);
                bool NE = lane < 63 && ((a >> (lane + 1)) & 1ULL);
                if (N) { if (!(W && NW)) uniteL(sg, t, t - TS); }
                else {
                    if (NW && !W) uniteL(sg, t, t - TS - 1);
                    if (NE && !E) uniteL(sg, t, t - TS + 1);
                }
            }
        }
    }
    __syncthreads();

    // phase 3: resolve + write global labels; collect tile roots as candidates
    for (int k = 0; k < 16; k++) {
        int lr = wv + (k << 2);
        int t = (lr << 6) + lane;
        int g = base + (lr << 9) + lane;
        int v = sp[t];
        if (v < TSQ) {
            int ro = findRootL(sp, t);
            int gl = ((r0 + (ro >> 6)) << 9) + (c0 + (ro & 63));
            labP[g] = gl;
            if (ro == t) { int pos = atomicAdd(&candCntP[b], 1); if (pos < CCAP) candP[b * CCAP + pos] = gl; }
        } else labP[g] = SENT;
        v = sg[t];
        if (v < TSQ) {
            int ro = findRootL(sg, t);
            int gl = ((r0 + (ro >> 6)) << 9) + (c0 + (ro & 63));
            labG[g] = gl;
            if (ro == t) { int pos = atomicAdd(&candCntG[b], 1); if (pos < CCAP) candG[b * CCAP + pos] = gl; }
        } else labG[g] = SENT;
    }
}

__device__ __forceinline__ void processB(int* L, int i, int r, int c, int kind) {
    if (L[i] >= SENT) return;
    if (kind == 1) {            // c%64==0, c>0: w and nw cross the tile edge
        if (L[i - 1] < SENT) unite(L, i, i - 1);
        if (r > 0 && L[i - WW - 1] < SENT) unite(L, i, i - WW - 1);
    } else if (kind == 2) {     // c%64==63, c<511: ne crosses
        if (r > 0 && c < WW - 1 && L[i - WW + 1] < SENT) unite(L, i, i - WW + 1);
    } else {                    // r%64==0, r>0: n, nw, ne cross
        if (L[i - WW] < SENT) unite(L, i, i - WW);
        if (c > 0 && L[i - WW - 1] < SENT) unite(L, i, i - WW - 1);
        if (c < WW - 1 && L[i - WW + 1] < SENT) unite(L, i, i - WW + 1);
    }
}

// Cross-tile merges only: 21 boundary lines x 512 per image per mask.
__global__ void k_bmerge(int* __restrict__ labP, int* __restrict__ labG) {
    const int PER = 21 * 512;
    int idx = blockIdx.x * blockDim.x + threadIdx.x;
    if (idx >= NB * PER) return;
    int b = idx / PER, rem = idx % PER;
    int kind = rem / (7 * 512);
    int q = (rem % (7 * 512)) >> 9;
    int u = rem & 511;
    int r, c;
    if (kind == 0)      { r = TS * (q + 1); c = u; }
    else if (kind == 1) { c = TS * (q + 1); r = u; }
    else                { c = TS * q + 63;  r = u; }
    int i = (r << 9) | c;
    processB(labP + (b << 18), i, r, c, kind);
    processB(labG + (b << 18), i, r, c, kind);
}

// Filter tile-root candidates down to true global roots.
__global__ void k_roots(const int* __restrict__ labP, const int* __restrict__ labG,
                        const int* __restrict__ candP, const int* __restrict__ candG,
                        const int* __restrict__ candCntP, const int* __restrict__ candCntG,
                        int* __restrict__ rootsP, int* __restrict__ rootsG,
                        int* __restrict__ cntP, int* __restrict__ cntG) {
    int b = blockIdx.x >> 5;            // 32 blocks of 256 = CCAP per image
    int t = ((blockIdx.x & 31) << 8) + threadIdx.x;
    int ncp = min(candCntP[b], CCAP);
    if (t < ncp) {
        int i = candP[b * CCAP + t];
        if (labP[(b << 18) + i] == i) {
            int pos = atomicAdd(&cntP[b], 1);
            if (pos < RCAP) rootsP[b * RCAP + pos] = i;
        }
    }
    int ncg = min(candCntG[b], CCAP);
    if (t < ncg) {
        int i = candG[b * CCAP + t];
        if (labG[(b << 18) + i] == i) {
            int pos = atomicAdd(&cntG[b], 1);
            if (pos < RCAP) rootsG[b * RCAP + pos] = i;
        }
    }
}

// one block per (image, mask): size-adaptive bitonic sort of roots ascending
__global__ void k_sort(const int* __restrict__ rootsP, const int* __restrict__ rootsG,
                       const int* __restrict__ cntP, const int* __restrict__ cntG,
                       int* __restrict__ compP, int* __restrict__ compG,
                       int* __restrict__ ccntP, int* __restrict__ ccntG) {
    __shared__ int s[RCAP];
    int b = blockIdx.x >> 1;
    int which = blockIdx.x & 1;
    const int* roots = which ? rootsG : rootsP;
    const int* cnt   = which ? cntG : cntP;
    int n = min(cnt[b], RCAP);
    for (int t = threadIdx.x; t < RCAP; t += blockDim.x)
        s[t] = (t < n) ? roots[b * RCAP + t] : IMAX;
    __syncthreads();
    int m = 1; while (m < n) m <<= 1;   // sort only next_pow2(n) elements
    for (int k = 2; k <= m; k <<= 1) {
        for (int j = k >> 1; j > 0; j >>= 1) {
            for (int t = threadIdx.x; t < m; t += blockDim.x) {
                int ixj = t ^ j;
                if (ixj > t) {
                    int a = s[t], bb = s[ixj];
                    bool up = ((t & k) == 0);
                    if ((a > bb) == up) { s[t] = bb; s[ixj] = a; }
                }
            }
            __syncthreads();
        }
    }
    int cc = min(n, KC);
    int* comp = which ? compG : compP;
    int* ccnt = which ? ccntG : ccntP;
    for (int t = threadIdx.x; t < KC; t += blockDim.x)
        comp[b * KC + t] = (t < cc) ? s[t] : IMAX;
    if (threadIdx.x == 0) ccnt[b] = cc;
}

// region stats; labels chased to root in-kernel; wave-uniform fast path
__global__ __launch_bounds__(TPB) void k_stats(const int* __restrict__ labP, const int* __restrict__ labG,
                        const int* __restrict__ compP, const int* __restrict__ compG,
                        int* __restrict__ pA, int* __restrict__ pR, int* __restrict__ pC,
                        int* __restrict__ gA, int* __restrict__ gR, int* __restrict__ gC,
                        int* __restrict__ ovP, int* __restrict__ ovG) {
    __shared__ int sLP[KC], sLG[KC];
    __shared__ int aP[KC], rP[KC], cP[KC], aG[KC], rG[KC], cG[KC];
    __shared__ int oP[KC], oG[KC];
    int b = blockIdx.x >> 7;            // 128 blocks per image, 2048 px each
    int blk = blockIdx.x & 127;
    for (int t = threadIdx.x; t < KC; t += TPB) {
        sLP[t] = compP[b * KC + t]; sLG[t] = compG[b * KC + t];
        aP[t] = rP[t] = cP[t] = 0; aG[t] = rG[t] = cG[t] = 0;
        oP[t] = oG[t] = 0;
    }
    __syncthreads();
    const int* LP = labP + (b << 18);
    const int* LG = labG + (b << 18);
    int lane = threadIdx.x & 63;
    int i0 = (blk << 11) + threadIdx.x;
    int lpv[8], lgv[8];
    #pragma unroll
    for (int k = 0; k < 8; k++) { lpv[k] = LP[i0 + (k << 8)]; lgv[k] = LG[i0 + (k << 8)]; }
    #pragma unroll
    for (int k = 0; k < 8; k++) {
        int i = i0 + (k << 8);
        int lp = lpv[k], lg = lgv[k];
        int r = i >> 9, c = i & 511;    // r uniform within a wave
        // pred side
        {
            bool set = lp < SENT;
            unsigned long long mb = __ballot(set);
            if (mb) {
                int src = __ffsll((long long)mb) - 1;
                int l0 = __shfl(lp, src);
                bool uni = __all(!set || lp == l0);
                bool ovl = __any(set && (lg < SENT));
                if (uni) {
                    int cid = bsearch_k(sLP, chaseRoot(LP, l0));
                    if (cid >= 0) {
                        int sc = set ? c : 0;
                        for (int o = 32; o; o >>= 1) sc += __shfl_xor(sc, o);
                        if (lane == src) {
                            int area = __popcll(mb);
                            atomicAdd(&aP[cid], area);
                            atomicAdd(&rP[cid], r * area);
                            atomicAdd(&cP[cid], sc);
                            if (ovl) oP[cid] = 1;
                        }
                    }
                } else if (set) {
                    int cid = bsearch_k(sLP, chaseRoot(LP, lp));
                    if (cid >= 0) {
                        atomicAdd(&aP[cid], 1); atomicAdd(&rP[cid], r); atomicAdd(&cP[cid], c);
                        if (lg < SENT) oP[cid] = 1;
                    }
                }
            }
        }
        // gt side
        {
            bool set = lg < SENT;
            unsigned long long mb = __ballot(set);
            if (mb) {
                int src = __ffsll((long long)mb) - 1;
                int l0 = __shfl(lg, src);
                bool uni = __all(!set || lg == l0);
                bool ovl = __any(set && (lp < SENT));
                if (uni) {
                    int cid = bsearch_k(sLG, chaseRoot(LG, l0));
                    if (cid >= 0) {
                        int sc = set ? c : 0;
                        for (int o = 32; o; o >>= 1) sc += __shfl_xor(sc, o);
                        if (lane == src) {
                            int area = __popcll(mb);
                            atomicAdd(&aG[cid], area);
                            atomicAdd(&rG[cid], r * area);
                            atomicAdd(&cG[cid], sc);
                            if (ovl) oG[cid] = 1;
                        }
                    }
                } else if (set) {
                    int cid = bsearch_k(sLG, chaseRoot(LG, lg));
                    if (cid >= 0) {
                        atomicAdd(&aG[cid], 1); atomicAdd(&rG[cid], r); atomicAdd(&cG[cid], c);
                        if (lp < SENT) oG[cid] = 1;
                    }
                }
            }
        }
    }
    __syncthreads();
    for (int t = threadIdx.x; t < KC; t += TPB) {
        if (aP[t]) { atomicAdd(&pA[b*KC+t], aP[t]); atomicAdd(&pR[b*KC+t], rP[t]); atomicAdd(&pC[b*KC+t], cP[t]); }
        if (oP[t]) atomicOr(&ovP[b*KC+t], 1);
        if (aG[t]) { atomicAdd(&gA[b*KC+t], aG[t]); atomicAdd(&gR[b*KC+t], rG[t]); atomicAdd(&gC[b*KC+t], cG[t]); }
        if (oG[t]) atomicOr(&ovG[b*KC+t], 1);
    }
}

// per-image: nearest gt centroid per pred region, region errors
__global__ void k_match(const int* __restrict__ pA, const int* __restrict__ pR, const int* __restrict__ pC,
                        const int* __restrict__ gA, const int* __restrict__ gR, const int* __restrict__ gC,
                        const int* __restrict__ ovP, const int* __restrict__ ccntP, const int* __restrict__ ccntG,
                        float* __restrict__ eP, float* __restrict__ eG) {
    __shared__ float sA[KC], sR[KC], sC[KC];
    int b = blockIdx.x;
    int t = threadIdx.x;                           // block = 512 = KC
    int ccg = ccntG[b], ccp = ccntP[b];
    {
        int a = gA[b * KC + t];
        float fa = (float)a;
        float d = fmaxf(fa, 1.0f);
        sA[t] = fa;
        sR[t] = (float)gR[b * KC + t] / d;
        sC[t] = (float)gC[b * KC + t] / d;
    }
    __syncthreads();
    float e_eff = 0.0f;
    int nn = 0;
    if (t < ccp) {
        float pa = (float)pA[b * KC + t];
        float dd = fmaxf(pa, 1.0f);
        float pcr = (float)pR[b * KC + t] / dd;
        float pcc = (float)pC[b * KC + t] / dd;
        float best = INFINITY;
        for (int gi = 0; gi < ccg; gi++) {
            float dr = pcr - sR[gi], dc = pcc - sC[gi];
            float d2 = dr * dr + dc * dc;
            if (d2 < best) { best = d2; nn = gi; }  // first-min ties like argmin
        }
        if (ccg > 0 && ovP[b * KC + t]) {
            float ratio = 1.0f - sA[nn] / dd;
            e_eff = fminf(fabsf(1.0f - expf(ratio)), 1.0f);
        }
    }
    eP[b * KC + t] = e_eff;
    if (e_eff > 0.0f) atomicMax((int*)&eG[b * KC + nn], __float_as_int(e_eff));
}

// per-pixel error rules + fused loss/metric reduction (labels chased in-kernel)
__global__ __launch_bounds__(TPB) void k_final(const float* __restrict__ in,
                        const int* __restrict__ labP, const int* __restrict__ labG,
                        const int* __restrict__ compP, const int* __restrict__ compG,
                        const int* __restrict__ ovP, const int* __restrict__ ovG,
                        const float* __restrict__ eP, const float* __restrict__ eG,
                        const int* __restrict__ ccntG, double* __restrict__ acc) {
    __shared__ int sLP[KC], sLG[KC], sOP[KC], sOG[KC];
    __shared__ float sEP[KC], sEG[KC];
    __shared__ float pLm[4], pPe[4];
    __shared__ int pCnt[4];
    int b = blockIdx.x >> 7;            // 128 blocks per image
    int blk = blockIdx.x & 127;
    for (int t = threadIdx.x; t < KC; t += TPB) {
        sLP[t] = compP[b*KC+t]; sLG[t] = compG[b*KC+t];
        sOP[t] = ovP[b*KC+t];   sOG[t] = ovG[b*KC+t];
        sEP[t] = eP[b*KC+t];    sEG[t] = eG[b*KC+t];
    }
    __syncthreads();
    const int* LP = labP + (b << 18);
    const int* LG = labG + (b << 18);
    bool hasGt = ccntG[b] > 0;
    int i0 = (blk << 11) + threadIdx.x;
    int lpv[8], lgv[8];
    #pragma unroll
    for (int k = 0; k < 8; k++) { lpv[k] = LP[i0 + (k << 8)]; lgv[k] = LG[i0 + (k << 8)]; }
    float aLm = 0.0f, aPe = 0.0f;
    int aCnt = 0;
    #pragma unroll
    for (int k = 0; k < 8; k++) {
        int lp = lpv[k], lg = lgv[k];
        bool pred = lp < SENT, gtm = lg < SENT;
        unsigned long long mAny = __ballot(pred || gtm);
        if (!mAny) continue;             // whole wave background
        // resolve compact ids (wave-uniform fast path)
        int cidP = -1;
        {
            unsigned long long mp = __ballot(pred);
            if (mp) {
                int src = __ffsll((long long)mp) - 1;
                int l0 = __shfl(lp, src);
                if (__all(!pred || lp == l0)) {
                    int cc = bsearch_k(sLP, chaseRoot(LP, l0));
                    if (pred) cidP = cc;
                } else if (pred) cidP = bsearch_k(sLP, chaseRoot(LP, lp));
            }
        }
        int cidG = -1;
        {
            unsigned long long mg = __ballot(gtm);
            if (mg) {
                int src = __ffsll((long long)mg) - 1;
                int l0 = __shfl(lg, src);
                if (__all(!gtm || lg == l0)) {
                    int cc = bsearch_k(sLG, chaseRoot(LG, l0));
                    if (gtm) cidG = cc;
                } else if (gtm) cidG = bsearch_k(sLG, chaseRoot(LG, lg));
            }
        }
        if (pred || gtm) {
            float pe = 0.0f;
            if (pred) {
                if (!hasGt) pe = 1.0f;
                else {
                    int ov = (cidP >= 0) ? sOP[cidP] : 1;
                    if (!ov) pe = 1.0f;
                    else if (!gtm) pe = (cidP >= 0) ? sEP[cidP] : 0.0f;
                }
            }
            if (gtm) {
                if (!pred) pe = fmaxf(pe, (cidG >= 0) ? sEG[cidG] : 0.0f);
                int ovg = (cidG >= 0) ? sOG[cidG] : 1;
                if (!ovg) pe = 1.0f;
            }
            if (pe != 0.0f) {
                float x = in[(b << 18) + i0 + (k << 8)];
                float score = 1.0f / (1.0f + expf(-x));
                aLm += (1.0f / (1.0f + expf(-(score + 1.0f) * pe)) - 0.5f) * 2.0f;
                aPe += pe;
                aCnt++;
            }
        }
    }
    for (int o = 32; o; o >>= 1) {
        aLm += __shfl_xor(aLm, o);
        aPe += __shfl_xor(aPe, o);
        aCnt += __shfl_xor(aCnt, o);
    }
    int wv = threadIdx.x >> 6, lane = threadIdx.x & 63;
    if (lane == 0) { pLm[wv] = aLm; pPe[wv] = aPe; pCnt[wv] = aCnt; }
    __syncthreads();
    if (threadIdx.x == 0) {
        double sl = 0, sp = 0; int sc = 0;
        for (int q = 0; q < 4; q++) { sl += pLm[q]; sp += pPe[q]; sc += pCnt[q]; }
        atomicAdd(&acc[0], sl);
        atomicAdd(&acc[1], sp);
        atomicAdd(&acc[2], (double)sc);
    }
}

__global__ void k_out(const double* __restrict__ acc, float* __restrict__ out) {
    out[0] = (float)(acc[0] / (double)PN);
    out[1] = (float)(1.0 - acc[1] / (double)PN);
    out[2] = (float)(1.0 - acc[1] / acc[2]);
}

extern "C" void kernel_launch(void* const* d_in, const int* in_sizes, int n_in,
                              void* d_out, int out_size, void* d_ws, size_t ws_size,
                              hipStream_t stream) {
    const float* in = (const float*)d_in[0];
    const float* tg = (const float*)d_in[1];
    // d_in[2] = epoch, unused by forward

    char* w = (char*)d_ws;
    size_t off = 0;
    int* labP = (int*)(w + off); off += (size_t)PN * 4;
    int* labG = (int*)(w + off); off += (size_t)PN * 4;
    int* candP = (int*)(w + off); off += (size_t)NB * CCAP * 4;
    int* candG = (int*)(w + off); off += (size_t)NB * CCAP * 4;
    int* rootsP = (int*)(w + off); off += (size_t)NB * RCAP * 4;
    int* rootsG = (int*)(w + off); off += (size_t)NB * RCAP * 4;
    size_t zoff = off;
    int* candCntP = (int*)(w + off); off += NB * 4;
    int* candCntG = (int*)(w + off); off += NB * 4;
    int* cntP  = (int*)(w + off); off += NB * 4;
    int* cntG  = (int*)(w + off); off += NB * 4;
    int* ccntP = (int*)(w + off); off += NB * 4;
    int* ccntG = (int*)(w + off); off += NB * 4;
    int* compP = (int*)(w + off); off += (size_t)NB * KC * 4;
    int* compG = (int*)(w + off); off += (size_t)NB * KC * 4;
    int* pA = (int*)(w + off); off += (size_t)NB * KC * 4;
    int* pR = (int*)(w + off); off += (size_t)NB * KC * 4;
    int* pC = (int*)(w + off); off += (size_t)NB * KC * 4;
    int* gA = (int*)(w + off); off += (size_t)NB * KC * 4;
    int* gR = (int*)(w + off); off += (size_t)NB * KC * 4;
    int* gC = (int*)(w + off); off += (size_t)NB * KC * 4;
    int* ovP = (int*)(w + off); off += (size_t)NB * KC * 4;
    int* ovG = (int*)(w + off); off += (size_t)NB * KC * 4;
    float* eP = (float*)(w + off); off += (size_t)NB * KC * 4;
    float* eG = (float*)(w + off); off += (size_t)NB * KC * 4;
    double* acc = (double*)(w + off); off += 4 * 8;

    // zero all control/stat/accumulator state (fresh every call)
    hipMemsetAsync(w + zoff, 0, off - zoff, stream);

    k_local<<<NB * 64, TPB, 0, stream>>>(in, tg, labP, labG, candP, candG, candCntP, candCntG);
    {
        const int total = NB * 21 * 512;
        k_bmerge<<<(total + TPB - 1) / TPB, TPB, 0, stream>>>(labP, labG);
    }
    k_roots<<<NB * 32, TPB, 0, stream>>>(labP, labG, candP, candG, candCntP, candCntG,
                                         rootsP, rootsG, cntP, cntG);
    k_sort<<<2 * NB, TPB, 0, stream>>>(rootsP, rootsG, cntP, cntG, compP, compG, ccntP, ccntG);
    k_stats<<<NB * 128, TPB, 0, stream>>>(labP, labG, compP, compG,
                                          pA, pR, pC, gA, gR, gC, ovP, ovG);
    k_match<<<NB, KC, 0, stream>>>(pA, pR, pC, gA, gR, gC, ovP, ccntP, ccntG, eP, eG);
    k_final<<<NB * 128, TPB, 0, stream>>>(in, labP, labG, compP, compG,
                                          ovP, ovG, eP, eG, ccntG, acc);
    k_out<<<1, 1, 0, stream>>>(acc, (float*)d_out);
}

// Round 5
// 235.738 us; speedup vs baseline: 1.1334x; 1.1334x over previous
//
#include <hip/hip_runtime.h>

#define NB 16
#define HH 512
#define WW 512
#define HWN (HH * WW)            // 262144 = 1<<18
#define SENT HWN                  // background sentinel
#define KC 512                    // max regions kept per image
#define RCAP 4096                 // root list capacity per image
#define CCAP 8192                 // tile-root candidate capacity per image
#define PN (NB * HWN)
#define TPB 256
#define IMAX 0x7FFFFFFF
#define TS 64                     // CCL tile side
#define TSQ (TS * TS)             // 4096, local sentinel

// ---------------- union-find helpers (global mem) ----------------
__device__ __forceinline__ int findRoot(int* L, int i) {
    int p = L[i];
    while (p != i) { i = p; p = L[i]; }
    return i;
}

__device__ __forceinline__ int chaseRoot(const int* __restrict__ L, int i) {
    int p = L[i];
    while (p != i) { i = p; p = L[i]; }
    return i;
}

__device__ __forceinline__ void unite(int* L, int a, int b) {
    int ra = findRoot(L, a);
    int rb = findRoot(L, b);
    while (ra != rb) {
        int lo = min(ra, rb), hi = max(ra, rb);
        int old = atomicMin(&L[hi], lo);
        if (old == hi) return;
        ra = old; rb = lo;
    }
}

// ---------------- union-find helpers (LDS) ----------------
__device__ __forceinline__ int findRootL(int* s, int i) {
    int p = s[i];
    while (p != i) { i = p; p = s[i]; }
    return i;
}

__device__ __forceinline__ void uniteL(int* s, int a, int b) {
    int ra = findRootL(s, a);
    int rb = findRootL(s, b);
    while (ra != rb) {
        int lo = min(ra, rb), hi = max(ra, rb);
        int old = atomicMin(&s[hi], lo);
        if (old == hi) return;
        ra = old; rb = lo;
    }
}

// binary search exact key in ascending array of KC ints (padded IMAX)
__device__ __forceinline__ int bsearch_k(const int* a, int key) {
    int lo = 0, hi = KC;
    while (lo < hi) { int m = (lo + hi) >> 1; if (a[m] < key) lo = m + 1; else hi = m; }
    return (lo < KC && a[lo] == key) ? lo : -1;
}

// ---------------- kernels ----------------
// Per-tile CCL: run-based labels (ballot), reduced union rules, all in LDS.
// Also appends tile-root pixels to the per-image root-candidate list.
__global__ __launch_bounds__(TPB) void k_local(const float* __restrict__ in, const float* __restrict__ tg,
                        int* __restrict__ labP, int* __restrict__ labG,
                        int* __restrict__ candP, int* __restrict__ candG,
                        int* __restrict__ candCntP, int* __restrict__ candCntG) {
    __shared__ int sp[TSQ];
    __shared__ int sg[TSQ];
    __shared__ unsigned long long rmP[TS], rmG[TS];
    int b = blockIdx.x >> 6;            // 64 tiles per image (8x8)
    int tile = blockIdx.x & 63;
    int r0 = (tile >> 3) << 6, c0 = (tile & 7) << 6;
    int base = (b << 18) + (r0 << 9) + c0;
    int wv = threadIdx.x >> 6, lane = threadIdx.x & 63;

    #pragma unroll
    for (int k = 0; k < 16; k++) {
        int lr = wv + (k << 2);
        bool p = in[base + (lr << 9) + lane] > 0.0f;   // sigmoid(x)>0.5 <=> x>0
        bool q = tg[base + (lr << 9) + lane] > 0.5f;
        unsigned long long mp = __ballot(p);
        unsigned long long mq = __ballot(q);
        int t = (lr << 6) + lane;
        unsigned long long below = (lane == 0) ? 0ULL : ((~mp) & ((1ULL << lane) - 1ULL));
        int st = below ? (64 - __clzll(below)) : 0;
        sp[t] = p ? ((lr << 6) + st) : TSQ;
        below = (lane == 0) ? 0ULL : ((~mq) & ((1ULL << lane) - 1ULL));
        st = below ? (64 - __clzll(below)) : 0;
        sg[t] = q ? ((lr << 6) + st) : TSQ;
        if (lane == 0) { rmP[lr] = mp; rmG[lr] = mq; }
    }
    __syncthreads();

    // inter-row unions, reduced rules (one union per adjacent run-pair)
    for (int lr = wv; lr < TS; lr += 4) {
        if (lr == 0) continue;
        int t = (lr << 6) + lane;
        {
            unsigned long long m = rmP[lr], a = rmP[lr - 1];
            if ((m >> lane) & 1ULL) {
                bool N  = (a >> lane) & 1ULL;
                bool W  = lane > 0  && ((m >> (lane - 1)) & 1ULL);
                bool NW = lane > 0  && ((a >> (lane - 1)) & 1ULL);
                bool E  = lane < 63 && ((m >> (lane + 1)) & 1ULL);
                bool NE = lane < 63 && ((a >> (lane + 1)) & 1ULL);
                if (N) { if (!(W && NW)) uniteL(sp, t, t - TS); }
                else {
                    if (NW && !W) uniteL(sp, t, t - TS - 1);
                    if (NE && !E) uniteL(sp, t, t - TS + 1);
                }
            }
        }
        {
            unsigned long long m = rmG[lr], a = rmG[lr - 1];
            if ((m >> lane) & 1ULL) {
                bool N  = (a >> lane) & 1ULL;
                bool W  = lane > 0  && ((m >> (lane - 1)) & 1ULL);
                bool NW = lane > 0  && ((a >> (lane - 1)) & 1ULL);
                bool E  = lane < 63 && ((m >> (lane + 1)) & 1ULL);
                bool NE = lane < 63 && ((a >> (lane + 1)) & 1ULL);
                if (N) { if (!(W && NW)) uniteL(sg, t, t - TS); }
                else {
                    if (NW && !W) uniteL(sg, t, t - TS - 1);
                    if (NE && !E) uniteL(sg, t, t - TS + 1);
                }
            }
        }
    }
    __syncthreads();

    // resolve + write global labels; collect tile roots as candidates
    for (int k = 0; k < 16; k++) {
        int lr = wv + (k << 2);
        int t = (lr << 6) + lane;
        int g = base + (lr << 9) + lane;
        int v = sp[t];
        if (v < TSQ) {
            int ro = findRootL(sp, t);
            int gl = ((r0 + (ro >> 6)) << 9) + (c0 + (ro & 63));
            labP[g] = gl;
            if (ro == t) { int pos = atomicAdd(&candCntP[b], 1); if (pos < CCAP) candP[b * CCAP + pos] = gl; }
        } else labP[g] = SENT;
        v = sg[t];
        if (v < TSQ) {
            int ro = findRootL(sg, t);
            int gl = ((r0 + (ro >> 6)) << 9) + (c0 + (ro & 63));
            labG[g] = gl;
            if (ro == t) { int pos = atomicAdd(&candCntG[b], 1); if (pos < CCAP) candG[b * CCAP + pos] = gl; }
        } else labG[g] = SENT;
    }
}

__device__ __forceinline__ void processB(int* L, int i, int r, int c, int kind) {
    if (L[i] >= SENT) return;
    if (kind == 1) {            // c%64==0, c>0: w and nw cross the tile edge
        if (L[i - 1] < SENT) unite(L, i, i - 1);
        if (r > 0 && L[i - WW - 1] < SENT) unite(L, i, i - WW - 1);
    } else if (kind == 2) {     // c%64==63, c<511: ne crosses
        if (r > 0 && c < WW - 1 && L[i - WW + 1] < SENT) unite(L, i, i - WW + 1);
    } else {                    // r%64==0, r>0: n, nw, ne cross
        if (L[i - WW] < SENT) unite(L, i, i - WW);
        if (c > 0 && L[i - WW - 1] < SENT) unite(L, i, i - WW - 1);
        if (c < WW - 1 && L[i - WW + 1] < SENT) unite(L, i, i - WW + 1);
    }
}

// Cross-tile merges only: 21 boundary lines x 512 per image per mask.
__global__ void k_bmerge(int* __restrict__ labP, int* __restrict__ labG) {
    const int PER = 21 * 512;
    int idx = blockIdx.x * blockDim.x + threadIdx.x;
    if (idx >= NB * PER) return;
    int b = idx / PER, rem = idx % PER;
    int kind = rem / (7 * 512);
    int q = (rem % (7 * 512)) >> 9;
    int u = rem & 511;
    int r, c;
    if (kind == 0)      { r = TS * (q + 1); c = u; }
    else if (kind == 1) { c = TS * (q + 1); r = u; }
    else                { c = TS * q + 63;  r = u; }
    int i = (r << 9) | c;
    processB(labP + (b << 18), i, r, c, kind);
    processB(labG + (b << 18), i, r, c, kind);
}

// one block per (image, mask): filter tile-root candidates to true roots (in LDS),
// size-adaptive bitonic sort ascending, compact first KC.
__global__ void k_sortroots(const int* __restrict__ labP, const int* __restrict__ labG,
                            const int* __restrict__ candP, const int* __restrict__ candG,
                            const int* __restrict__ candCntP, const int* __restrict__ candCntG,
                            int* __restrict__ compP, int* __restrict__ compG,
                            int* __restrict__ ccntP, int* __restrict__ ccntG) {
    __shared__ int s[RCAP];
    __shared__ int lcnt;
    int b = blockIdx.x >> 1;
    int which = blockIdx.x & 1;
    const int* cand = which ? candG : candP;
    const int* L = (which ? labG : labP) + (b << 18);
    int nc = min((which ? candCntG : candCntP)[b], CCAP);
    if (threadIdx.x == 0) lcnt = 0;
    __syncthreads();
    for (int t = threadIdx.x; t < nc; t += TPB) {
        int i = cand[b * CCAP + t];
        if (L[i] == i) { int pos = atomicAdd(&lcnt, 1); if (pos < RCAP) s[pos] = i; }
    }
    __syncthreads();
    int n = min(lcnt, RCAP);
    int m = 1; while (m < n) m <<= 1;
    for (int t = n + threadIdx.x; t < m; t += TPB) s[t] = IMAX;
    __syncthreads();
    for (int k = 2; k <= m; k <<= 1) {
        for (int j = k >> 1; j > 0; j >>= 1) {
            for (int t = threadIdx.x; t < m; t += TPB) {
                int ixj = t ^ j;
                if (ixj > t) {
                    int a = s[t], bb = s[ixj];
                    bool up = ((t & k) == 0);
                    if ((a > bb) == up) { s[t] = bb; s[ixj] = a; }
                }
            }
            __syncthreads();
        }
    }
    int cc = min(n, KC);
    int* comp = which ? compG : compP;
    int* ccnt = which ? ccntG : ccntP;
    for (int t = threadIdx.x; t < KC; t += TPB)
        comp[b * KC + t] = (t < cc) ? s[t] : IMAX;
    if (threadIdx.x == 0) ccnt[b] = cc;
}

// region stats + RELABEL: writes packed compact ids per pixel.
// encoding per 16-bit field: 0 = background, 1 = fg w/o compact id, cid+2 otherwise.
__global__ __launch_bounds__(TPB) void k_stats(const int* __restrict__ labP, const int* __restrict__ labG,
                        const int* __restrict__ compP, const int* __restrict__ compG,
                        int* __restrict__ cidArr,
                        int* __restrict__ pA, int* __restrict__ pR, int* __restrict__ pC,
                        int* __restrict__ gA, int* __restrict__ gR, int* __restrict__ gC,
                        int* __restrict__ ovP, int* __restrict__ ovG) {
    __shared__ int sLP[KC], sLG[KC];
    __shared__ int aP[KC], rP[KC], cP[KC], aG[KC], rG[KC], cG[KC];
    __shared__ int oP[KC], oG[KC];
    int b = blockIdx.x >> 6;            // 64 blocks per image, 4096 px each
    int blk = blockIdx.x & 63;
    for (int t = threadIdx.x; t < KC; t += TPB) {
        sLP[t] = compP[b * KC + t]; sLG[t] = compG[b * KC + t];
        aP[t] = rP[t] = cP[t] = 0; aG[t] = rG[t] = cG[t] = 0;
        oP[t] = oG[t] = 0;
    }
    __syncthreads();
    const int* LP = labP + (b << 18);
    const int* LG = labG + (b << 18);
    int lane = threadIdx.x & 63;
    int i0 = (blk << 12) + threadIdx.x;
    #pragma unroll
    for (int k = 0; k < 16; k++) {
        int i = i0 + (k << 8);
        int lp = LP[i], lg = LG[i];
        int r = i >> 9, c = i & 511;    // r uniform within a wave
        int fp = 0, fg = 0;
        // pred side
        {
            bool set = lp < SENT;
            unsigned long long mb = __ballot(set);
            if (mb) {
                int src = __ffsll((long long)mb) - 1;
                int l0 = __shfl(lp, src);
                if (__all(!set || lp == l0)) {
                    int cid = bsearch_k(sLP, chaseRoot(LP, l0));  // uniform: broadcast loads
                    if (set) fp = cid + 2;
                    if (cid >= 0) {
                        int sc = set ? c : 0;
                        for (int o = 32; o; o >>= 1) sc += __shfl_xor(sc, o);
                        bool ovl = __any(set && (lg < SENT));
                        if (lane == src) {
                            int area = __popcll(mb);
                            atomicAdd(&aP[cid], area);
                            atomicAdd(&rP[cid], r * area);
                            atomicAdd(&cP[cid], sc);
                            if (ovl) oP[cid] = 1;
                        }
                    }
                } else if (set) {
                    int cid = bsearch_k(sLP, chaseRoot(LP, lp));
                    fp = cid + 2;
                    if (cid >= 0) {
                        atomicAdd(&aP[cid], 1); atomicAdd(&rP[cid], r); atomicAdd(&cP[cid], c);
                        if (lg < SENT) oP[cid] = 1;
                    }
                }
            }
        }
        // gt side
        {
            bool set = lg < SENT;
            unsigned long long mb = __ballot(set);
            if (mb) {
                int src = __ffsll((long long)mb) - 1;
                int l0 = __shfl(lg, src);
                if (__all(!set || lg == l0)) {
                    int cid = bsearch_k(sLG, chaseRoot(LG, l0));
                    if (set) fg = cid + 2;
                    if (cid >= 0) {
                        int sc = set ? c : 0;
                        for (int o = 32; o; o >>= 1) sc += __shfl_xor(sc, o);
                        bool ovl = __any(set && (lp < SENT));
                        if (lane == src) {
                            int area = __popcll(mb);
                            atomicAdd(&aG[cid], area);
                            atomicAdd(&rG[cid], r * area);
                            atomicAdd(&cG[cid], sc);
                            if (ovl) oG[cid] = 1;
                        }
                    }
                } else if (set) {
                    int cid = bsearch_k(sLG, chaseRoot(LG, lg));
                    fg = cid + 2;
                    if (cid >= 0) {
                        atomicAdd(&aG[cid], 1); atomicAdd(&rG[cid], r); atomicAdd(&cG[cid], c);
                        if (lp < SENT) oG[cid] = 1;
                    }
                }
            }
        }
        cidArr[(b << 18) + i] = fp | (fg << 16);
    }
    __syncthreads();
    for (int t = threadIdx.x; t < KC; t += TPB) {
        if (aP[t]) { atomicAdd(&pA[b*KC+t], aP[t]); atomicAdd(&pR[b*KC+t], rP[t]); atomicAdd(&pC[b*KC+t], cP[t]); }
        if (oP[t]) atomicOr(&ovP[b*KC+t], 1);
        if (aG[t]) { atomicAdd(&gA[b*KC+t], aG[t]); atomicAdd(&gR[b*KC+t], rG[t]); atomicAdd(&gC[b*KC+t], cG[t]); }
        if (oG[t]) atomicOr(&ovG[b*KC+t], 1);
    }
}

// per-image: nearest gt centroid per pred region, region errors.
// Packs (overlap, error) per region: f = ov ? e : -1.0
__global__ void k_match(const int* __restrict__ pA, const int* __restrict__ pR, const int* __restrict__ pC,
                        const int* __restrict__ gA, const int* __restrict__ gR, const int* __restrict__ gC,
                        const int* __restrict__ ovP, const int* __restrict__ ovG,
                        const int* __restrict__ ccntP, const int* __restrict__ ccntG,
                        float* __restrict__ fP, float* __restrict__ fG) {
    __shared__ float sA[KC], sR[KC], sC[KC];
    __shared__ float sEG[KC];
    int b = blockIdx.x;
    int t = threadIdx.x;                           // block = 512 = KC
    int ccg = ccntG[b], ccp = ccntP[b];
    {
        int a = gA[b * KC + t];
        float fa = (float)a;
        float d = fmaxf(fa, 1.0f);
        sA[t] = fa;
        sR[t] = (float)gR[b * KC + t] / d;
        sC[t] = (float)gC[b * KC + t] / d;
        sEG[t] = 0.0f;
    }
    __syncthreads();
    float e_eff = 0.0f;
    int nn = 0;
    if (t < ccp) {
        float pa = (float)pA[b * KC + t];
        float dd = fmaxf(pa, 1.0f);
        float pcr = (float)pR[b * KC + t] / dd;
        float pcc = (float)pC[b * KC + t] / dd;
        float best = INFINITY;
        for (int gi = 0; gi < ccg; gi++) {
            float dr = pcr - sR[gi], dc = pcc - sC[gi];
            float d2 = dr * dr + dc * dc;
            if (d2 < best) { best = d2; nn = gi; }  // first-min ties like argmin
        }
        if (ccg > 0 && ovP[b * KC + t]) {
            float ratio = 1.0f - sA[nn] / dd;
            e_eff = fminf(fabsf(1.0f - expf(ratio)), 1.0f);
        }
    }
    if (e_eff > 0.0f) atomicMax((int*)&sEG[nn], __float_as_int(e_eff));
    fP[b * KC + t] = ovP[b * KC + t] ? e_eff : -1.0f;
    __syncthreads();
    fG[b * KC + t] = ovG[b * KC + t] ? fmaxf(sEG[t], 0.0f) : -1.0f;
}

// per-pixel error rules + fused loss/metric reduction: pure table lookups
__global__ __launch_bounds__(TPB) void k_final(const float* __restrict__ in,
                        const int* __restrict__ cidArr,
                        const float* __restrict__ fP, const float* __restrict__ fG,
                        const int* __restrict__ ccntG, double* __restrict__ acc) {
    __shared__ float sFP[KC], sFG[KC];
    __shared__ float pLm[4], pPe[4];
    __shared__ int pCnt[4];
    int b = blockIdx.x >> 6;            // 64 blocks per image
    int blk = blockIdx.x & 63;
    for (int t = threadIdx.x; t < KC; t += TPB) {
        sFP[t] = fP[b*KC+t]; sFG[t] = fG[b*KC+t];
    }
    __syncthreads();
    bool hasGt = ccntG[b] > 0;
    int i0 = (blk << 12) + threadIdx.x;
    float aLm = 0.0f, aPe = 0.0f;
    int aCnt = 0;
    #pragma unroll
    for (int k = 0; k < 16; k++) {
        int g = (b << 18) + i0 + (k << 8);
        int f = cidArr[g];
        float x = in[g];
        if (!__any(f != 0)) continue;    // whole wave background
        int fp = f & 0xffff;
        int fg = (f >> 16) & 0xffff;
        float pe = 0.0f;
        if (fp) {
            if (!hasGt) pe = 1.0f;
            else if (fp >= 2) {
                float v = sFP[fp - 2];
                if (v < 0.0f) pe = 1.0f;          // pred region w/o overlap
                else if (!fg) pe = v;             // pred px, gt!=1
            }
        }
        if (fg) {
            float vg = (fg >= 2) ? sFG[fg - 2] : 0.0f;
            if (!fp) pe = fmaxf(pe, fmaxf(vg, 0.0f));   // gt px, pred<1
            if (vg < 0.0f) pe = 1.0f;                    // gt region w/o overlap
        }
        if (pe != 0.0f) {
            float score = 1.0f / (1.0f + expf(-x));
            aLm += (1.0f / (1.0f + expf(-(score + 1.0f) * pe)) - 0.5f) * 2.0f;
            aPe += pe;
            aCnt++;
        }
    }
    for (int o = 32; o; o >>= 1) {
        aLm += __shfl_xor(aLm, o);
        aPe += __shfl_xor(aPe, o);
        aCnt += __shfl_xor(aCnt, o);
    }
    int wv = threadIdx.x >> 6, lane = threadIdx.x & 63;
    if (lane == 0) { pLm[wv] = aLm; pPe[wv] = aPe; pCnt[wv] = aCnt; }
    __syncthreads();
    if (threadIdx.x == 0) {
        double sl = 0, sp = 0; int sc = 0;
        for (int q = 0; q < 4; q++) { sl += pLm[q]; sp += pPe[q]; sc += pCnt[q]; }
        atomicAdd(&acc[0], sl);
        atomicAdd(&acc[1], sp);
        atomicAdd(&acc[2], (double)sc);
    }
}

__global__ void k_out(const double* __restrict__ acc, float* __restrict__ out) {
    out[0] = (float)(acc[0] / (double)PN);
    out[1] = (float)(1.0 - acc[1] / (double)PN);
    out[2] = (float)(1.0 - acc[1] / acc[2]);
}

extern "C" void kernel_launch(void* const* d_in, const int* in_sizes, int n_in,
                              void* d_out, int out_size, void* d_ws, size_t ws_size,
                              hipStream_t stream) {
    const float* in = (const float*)d_in[0];
    const float* tg = (const float*)d_in[1];
    // d_in[2] = epoch, unused by forward

    char* w = (char*)d_ws;
    size_t off = 0;
    int* labP = (int*)(w + off); off += (size_t)PN * 4;
    int* labG = (int*)(w + off); off += (size_t)PN * 4;
    int* cidArr = (int*)(w + off); off += (size_t)PN * 4;
    int* candP = (int*)(w + off); off += (size_t)NB * CCAP * 4;
    int* candG = (int*)(w + off); off += (size_t)NB * CCAP * 4;
    size_t zoff = off;
    int* candCntP = (int*)(w + off); off += NB * 4;
    int* candCntG = (int*)(w + off); off += NB * 4;
    int* ccntP = (int*)(w + off); off += NB * 4;
    int* ccntG = (int*)(w + off); off += NB * 4;
    int* pA = (int*)(w + off); off += (size_t)NB * KC * 4;
    int* pR = (int*)(w + off); off += (size_t)NB * KC * 4;
    int* pC = (int*)(w + off); off += (size_t)NB * KC * 4;
    int* gA = (int*)(w + off); off += (size_t)NB * KC * 4;
    int* gR = (int*)(w + off); off += (size_t)NB * KC * 4;
    int* gC = (int*)(w + off); off += (size_t)NB * KC * 4;
    int* ovP = (int*)(w + off); off += (size_t)NB * KC * 4;
    int* ovG = (int*)(w + off); off += (size_t)NB * KC * 4;
    double* acc = (double*)(w + off); off += 4 * 8;
    size_t zend = off;
    int* compP = (int*)(w + off); off += (size_t)NB * KC * 4;
    int* compG = (int*)(w + off); off += (size_t)NB * KC * 4;
    float* fP = (float*)(w + off); off += (size_t)NB * KC * 4;
    float* fG = (float*)(w + off); off += (size_t)NB * KC * 4;

    // zero control/stat/accumulator state (fresh every call)
    hipMemsetAsync(w + zoff, 0, zend - zoff, stream);

    k_local<<<NB * 64, TPB, 0, stream>>>(in, tg, labP, labG, candP, candG, candCntP, candCntG);
    {
        const int total = NB * 21 * 512;
        k_bmerge<<<(total + TPB - 1) / TPB, TPB, 0, stream>>>(labP, labG);
    }
    k_sortroots<<<2 * NB, TPB, 0, stream>>>(labP, labG, candP, candG, candCntP, candCntG,
                                            compP, compG, ccntP, ccntG);
    k_stats<<<NB * 64, TPB, 0, stream>>>(labP, labG, compP, compG, cidArr,
                                         pA, pR, pC, gA, gR, gC, ovP, ovG);
    k_match<<<NB, KC, 0, stream>>>(pA, pR, pC, gA, gR, gC, ovP, ovG, ccntP, ccntG, fP, fG);
    k_final<<<NB * 64, TPB, 0, stream>>>(in, cidArr, fP, fG, ccntG, acc);
    k_out<<<1, 1, 0, stream>>>(acc, (float*)d_out);
}

// Round 6
// 214.407 us; speedup vs baseline: 1.2462x; 1.0995x over previous
//
#include <hip/hip_runtime.h>

#define NB 16
#define HH 512
#define WW 512
#define HWN (HH * WW)            // 262144 = 1<<18
#define SENT HWN                  // background sentinel
#define KC 512                    // max regions kept per image
#define RCAP 4096                 // root list capacity per image
#define CCAP 4096                 // tile-root slot capacity per image
#define PN (NB * HWN)
#define TPB 256
#define IMAX 0x7FFFFFFF
#define TS 64                     // CCL tile side
#define TSQ (TS * TS)             // 4096, local sentinel

// ---------------- union-find helpers (global mem) ----------------
__device__ __forceinline__ int findRoot(int* L, int i) {
    int p = L[i];
    while (p != i) { i = p; p = L[i]; }
    return i;
}

__device__ __forceinline__ int chaseRoot(const int* __restrict__ L, int i) {
    int p = L[i];
    while (p != i) { i = p; p = L[i]; }
    return i;
}

__device__ __forceinline__ void unite(int* L, int a, int b) {
    int ra = findRoot(L, a);
    int rb = findRoot(L, b);
    while (ra != rb) {
        int lo = min(ra, rb), hi = max(ra, rb);
        int old = atomicMin(&L[hi], lo);
        if (old == hi) return;
        ra = old; rb = lo;
    }
}

// ---------------- union-find helpers (LDS) ----------------
__device__ __forceinline__ int findRootL(int* s, int i) {
    int p = s[i];
    while (p != i) { i = p; p = s[i]; }
    return i;
}

__device__ __forceinline__ void uniteL(int* s, int a, int b) {
    int ra = findRootL(s, a);
    int rb = findRootL(s, b);
    while (ra != rb) {
        int lo = min(ra, rb), hi = max(ra, rb);
        int old = atomicMin(&s[hi], lo);
        if (old == hi) return;
        ra = old; rb = lo;
    }
}

// binary search exact key in ascending array of KC ints (padded IMAX)
__device__ __forceinline__ int bsearch_k(const int* a, int key) {
    int lo = 0, hi = KC;
    while (lo < hi) { int m = (lo + hi) >> 1; if (a[m] < key) lo = m + 1; else hi = m; }
    return (lo < KC && a[lo] == key) ? lo : -1;
}

// ---------------- kernels ----------------
// Per-tile CCL: run-based labels (ballot), reduced union rules, all in LDS.
// Assigns per-image slots to tile roots, accumulates RUN-level stats into
// slot-indexed arrays, writes per-pixel packed slot pair, and writes
// union-find labels only for root + tile-edge pixels.
__global__ __launch_bounds__(TPB) void k_local(const float* __restrict__ in, const float* __restrict__ tg,
                        int* __restrict__ labP, int* __restrict__ labG,
                        int* __restrict__ slotPacked,
                        int* __restrict__ candP, int* __restrict__ candG,
                        int* __restrict__ candCntP, int* __restrict__ candCntG,
                        int* __restrict__ sAreaP, int* __restrict__ sRP, int* __restrict__ sCP, int* __restrict__ sOvP,
                        int* __restrict__ sAreaG, int* __restrict__ sRG, int* __restrict__ sCG, int* __restrict__ sOvG) {
    __shared__ int sp[TSQ];
    __shared__ int sg[TSQ];
    __shared__ unsigned long long rmP[TS], rmG[TS];
    int b = blockIdx.x >> 6;            // 64 tiles per image (8x8)
    int tile = blockIdx.x & 63;
    int r0 = (tile >> 3) << 6, c0 = (tile & 7) << 6;
    int base = (b << 18) + (r0 << 9) + c0;
    int wv = threadIdx.x >> 6, lane = threadIdx.x & 63;

    // phase 1: load, ballot row masks, run-start initial labels (no atomics)
    #pragma unroll
    for (int k = 0; k < 16; k++) {
        int lr = wv + (k << 2);
        bool p = in[base + (lr << 9) + lane] > 0.0f;   // sigmoid(x)>0.5 <=> x>0
        bool q = tg[base + (lr << 9) + lane] > 0.5f;
        unsigned long long mp = __ballot(p);
        unsigned long long mq = __ballot(q);
        int t = (lr << 6) + lane;
        unsigned long long below = (lane == 0) ? 0ULL : ((~mp) & ((1ULL << lane) - 1ULL));
        int st = below ? (64 - __clzll(below)) : 0;
        sp[t] = p ? ((lr << 6) + st) : TSQ;
        below = (lane == 0) ? 0ULL : ((~mq) & ((1ULL << lane) - 1ULL));
        st = below ? (64 - __clzll(below)) : 0;
        sg[t] = q ? ((lr << 6) + st) : TSQ;
        if (lane == 0) { rmP[lr] = mp; rmG[lr] = mq; }
    }
    __syncthreads();

    // phase 2: inter-row unions, reduced rules
    for (int lr = wv; lr < TS; lr += 4) {
        if (lr == 0) continue;
        int t = (lr << 6) + lane;
        {
            unsigned long long m = rmP[lr], a = rmP[lr - 1];
            if ((m >> lane) & 1ULL) {
                bool N  = (a >> lane) & 1ULL;
                bool W  = lane > 0  && ((m >> (lane - 1)) & 1ULL);
                bool NW = lane > 0  && ((a >> (lane - 1)) & 1ULL);
                bool E  = lane < 63 && ((m >> (lane + 1)) & 1ULL);
                bool NE = lane < 63 && ((a >> (lane + 1)) & 1ULL);
                if (N) { if (!(W && NW)) uniteL(sp, t, t - TS); }
                else {
                    if (NW && !W) uniteL(sp, t, t - TS - 1);
                    if (NE && !E) uniteL(sp, t, t - TS + 1);
                }
            }
        }
        {
            unsigned long long m = rmG[lr], a = rmG[lr - 1];
            if ((m >> lane) & 1ULL) {
                bool N  = (a >> lane) & 1ULL;
                bool W  = lane > 0  && ((m >> (lane - 1)) & 1ULL);
                bool NW = lane > 0  && ((a >> (lane - 1)) & 1ULL);
                bool E  = lane < 63 && ((m >> (lane + 1)) & 1ULL);
                bool NE = lane < 63 && ((a >> (lane + 1)) & 1ULL);
                if (N) { if (!(W && NW)) uniteL(sg, t, t - TS); }
                else {
                    if (NW && !W) uniteL(sg, t, t - TS - 1);
                    if (NE && !E) uniteL(sg, t, t - TS + 1);
                }
            }
        }
    }
    __syncthreads();

    // phase 3a: full path compression (racy-but-monotone, safe)
    #pragma unroll
    for (int k = 0; k < 16; k++) {
        int t = ((wv + (k << 2)) << 6) + lane;
        if (sp[t] < TSQ) sp[t] = findRootL(sp, t);
        if (sg[t] < TSQ) sg[t] = findRootL(sg, t);
    }
    __syncthreads();

    // phase 3b: roots -> slots (encode negative), collect candidates, write root labels
    #pragma unroll
    for (int k = 0; k < 16; k++) {
        int t = ((wv + (k << 2)) << 6) + lane;
        if (sp[t] == t) {
            int pos = atomicAdd(&candCntP[b], 1);
            if (pos >= CCAP) pos = CCAP - 1;
            int gl = ((r0 + (t >> 6)) << 9) + (c0 + (t & 63));
            candP[b * CCAP + pos] = gl;
            labP[(b << 18) + gl] = gl;
            sp[t] = -(pos + 2);
        }
        if (sg[t] == t) {
            int pos = atomicAdd(&candCntG[b], 1);
            if (pos >= CCAP) pos = CCAP - 1;
            int gl = ((r0 + (t >> 6)) << 9) + (c0 + (t & 63));
            candG[b * CCAP + pos] = gl;
            labG[(b << 18) + gl] = gl;
            sg[t] = -(pos + 2);
        }
    }
    __syncthreads();

    // phase 3c: per-pixel packed slot write + edge labels + per-run stats
    #pragma unroll
    for (int k = 0; k < 16; k++) {
        int lr = wv + (k << 2);
        int t = (lr << 6) + lane;
        int gli = ((r0 + lr) << 9) + (c0 + lane);
        int g = (b << 18) + gli;
        int vp = sp[t], vg = sg[t];
        int pSlot = 0, pRootT = -1;
        if (vp != TSQ) {
            if (vp < 0) { pRootT = t; pSlot = -vp - 1; }
            else        { pRootT = vp; pSlot = -sp[vp] - 1; }
        }
        int gSlot = 0, gRootT = -1;
        if (vg != TSQ) {
            if (vg < 0) { gRootT = t; gSlot = -vg - 1; }
            else        { gRootT = vg; gSlot = -sg[vg] - 1; }
        }
        slotPacked[g] = pSlot | (gSlot << 16);
        bool edge = (lr == 0) || (lr == 63) || (lane == 0) || (lane == 63);
        if (edge) {
            labP[g] = (pRootT >= 0) ? (((r0 + (pRootT >> 6)) << 9) + (c0 + (pRootT & 63))) : SENT;
            labG[g] = (gRootT >= 0) ? (((r0 + (gRootT >> 6)) << 9) + (c0 + (gRootT & 63))) : SENT;
        }
        // run stats (run-start lanes only)
        unsigned long long mp = rmP[lr], mq = rmG[lr];
        bool isP = (mp >> lane) & 1ULL;
        if (isP && (lane == 0 || !((mp >> (lane - 1)) & 1ULL))) {
            unsigned long long x = ~(mp >> lane);
            int len = x ? (__ffsll((long long)x) - 1) : (64 - lane);
            int slot = pSlot - 1;
            unsigned long long runbits = (len >= 64) ? ~0ULL : (((1ULL << len) - 1ULL) << lane);
            atomicAdd(&sAreaP[b * CCAP + slot], len);
            atomicAdd(&sRP[b * CCAP + slot], (r0 + lr) * len);
            atomicAdd(&sCP[b * CCAP + slot], len * (c0 + lane) + (len * (len - 1)) / 2);
            if (mq & runbits) atomicOr(&sOvP[b * CCAP + slot], 1);
        }
        bool isG = (mq >> lane) & 1ULL;
        if (isG && (lane == 0 || !((mq >> (lane - 1)) & 1ULL))) {
            unsigned long long x = ~(mq >> lane);
            int len = x ? (__ffsll((long long)x) - 1) : (64 - lane);
            int slot = gSlot - 1;
            unsigned long long runbits = (len >= 64) ? ~0ULL : (((1ULL << len) - 1ULL) << lane);
            atomicAdd(&sAreaG[b * CCAP + slot], len);
            atomicAdd(&sRG[b * CCAP + slot], (r0 + lr) * len);
            atomicAdd(&sCG[b * CCAP + slot], len * (c0 + lane) + (len * (len - 1)) / 2);
            if (mp & runbits) atomicOr(&sOvG[b * CCAP + slot], 1);
        }
    }
}

__device__ __forceinline__ void processB(int* L, int i, int r, int c, int kind) {
    if (L[i] >= SENT) return;
    if (kind == 1) {            // c%64==0, c>0: w and nw cross the tile edge
        if (L[i - 1] < SENT) unite(L, i, i - 1);
        if (r > 0 && L[i - WW - 1] < SENT) unite(L, i, i - WW - 1);
    } else if (kind == 2) {     // c%64==63, c<511: ne crosses
        if (r > 0 && c < WW - 1 && L[i - WW + 1] < SENT) unite(L, i, i - WW + 1);
    } else {                    // r%64==0, r>0: n, nw, ne cross
        if (L[i - WW] < SENT) unite(L, i, i - WW);
        if (c > 0 && L[i - WW - 1] < SENT) unite(L, i, i - WW - 1);
        if (c < WW - 1 && L[i - WW + 1] < SENT) unite(L, i, i - WW + 1);
    }
}

// Cross-tile merges only: 21 boundary lines x 512 per image per mask.
__global__ void k_bmerge(int* __restrict__ labP, int* __restrict__ labG) {
    const int PER = 21 * 512;
    int idx = blockIdx.x * blockDim.x + threadIdx.x;
    if (idx >= NB * PER) return;
    int b = idx / PER, rem = idx % PER;
    int kind = rem / (7 * 512);
    int q = (rem % (7 * 512)) >> 9;
    int u = rem & 511;
    int r, c;
    if (kind == 0)      { r = TS * (q + 1); c = u; }
    else if (kind == 1) { c = TS * (q + 1); r = u; }
    else                { c = TS * q + 63;  r = u; }
    int i = (r << 9) | c;
    processB(labP + (b << 18), i, r, c, kind);
    processB(labG + (b << 18), i, r, c, kind);
}

// one block per (image, mask): filter tile-root candidates to true roots (in LDS),
// size-adaptive bitonic sort ascending, compact first KC.
__global__ void k_sortroots(const int* __restrict__ labP, const int* __restrict__ labG,
                            const int* __restrict__ candP, const int* __restrict__ candG,
                            const int* __restrict__ candCntP, const int* __restrict__ candCntG,
                            int* __restrict__ compP, int* __restrict__ compG,
                            int* __restrict__ ccntP, int* __restrict__ ccntG) {
    __shared__ int s[RCAP];
    __shared__ int lcnt;
    int b = blockIdx.x >> 1;
    int which = blockIdx.x & 1;
    const int* cand = which ? candG : candP;
    const int* L = (which ? labG : labP) + (b << 18);
    int nc = min((which ? candCntG : candCntP)[b], CCAP);
    if (threadIdx.x == 0) lcnt = 0;
    __syncthreads();
    for (int t = threadIdx.x; t < nc; t += TPB) {
        int i = cand[b * CCAP + t];
        if (L[i] == i) { int pos = atomicAdd(&lcnt, 1); if (pos < RCAP) s[pos] = i; }
    }
    __syncthreads();
    int n = min(lcnt, RCAP);
    int m = 1; while (m < n) m <<= 1;
    for (int t = n + threadIdx.x; t < m; t += TPB) s[t] = IMAX;
    __syncthreads();
    for (int k = 2; k <= m; k <<= 1) {
        for (int j = k >> 1; j > 0; j >>= 1) {
            for (int t = threadIdx.x; t < m; t += TPB) {
                int ixj = t ^ j;
                if (ixj > t) {
                    int a = s[t], bb = s[ixj];
                    bool up = ((t & k) == 0);
                    if ((a > bb) == up) { s[t] = bb; s[ixj] = a; }
                }
            }
            __syncthreads();
        }
    }
    int cc = min(n, KC);
    int* comp = which ? compG : compP;
    int* ccnt = which ? ccntG : ccntP;
    for (int t = threadIdx.x; t < KC; t += TPB)
        comp[b * KC + t] = (t < cc) ? s[t] : IMAX;
    if (threadIdx.x == 0) ccnt[b] = cc;
}

// Per-slot: chase tile-root to global root, map to compact id, aggregate stats.
__global__ void k_redux(const int* __restrict__ labP, const int* __restrict__ labG,
                        const int* __restrict__ candP, const int* __restrict__ candG,
                        const int* __restrict__ candCntP, const int* __restrict__ candCntG,
                        const int* __restrict__ compP, const int* __restrict__ compG,
                        const int* __restrict__ sAreaP, const int* __restrict__ sRP, const int* __restrict__ sCP, const int* __restrict__ sOvP,
                        const int* __restrict__ sAreaG, const int* __restrict__ sRG, const int* __restrict__ sCG, const int* __restrict__ sOvG,
                        int* __restrict__ pA, int* __restrict__ pR, int* __restrict__ pC, int* __restrict__ ovP,
                        int* __restrict__ gA, int* __restrict__ gR, int* __restrict__ gC, int* __restrict__ ovG,
                        int* __restrict__ slotCidP, int* __restrict__ slotCidG) {
    int chunk = blockIdx.x & ((CCAP / TPB) - 1);
    int side = (blockIdx.x >> 4) & 1;            // CCAP/TPB = 16
    int b = blockIdx.x >> 5;
    int slot = (chunk << 8) + threadIdx.x;
    const int* cand = side ? candG : candP;
    const int* L = (side ? labG : labP) + (b << 18);
    const int* comp = (side ? compG : compP) + b * KC;
    int n = min((side ? candCntG : candCntP)[b], CCAP);
    if (slot >= n) return;
    int rootPx = cand[b * CCAP + slot];
    int gr = chaseRoot(L, rootPx);
    int cid = bsearch_k(comp, gr);
    (side ? slotCidG : slotCidP)[b * CCAP + slot] = cid;
    if (cid >= 0) {
        int idx = b * KC + cid;
        int sidx = b * CCAP + slot;
        if (side) {
            atomicAdd(&gA[idx], sAreaG[sidx]);
            atomicAdd(&gR[idx], sRG[sidx]);
            atomicAdd(&gC[idx], sCG[sidx]);
            if (sOvG[sidx]) atomicOr(&ovG[idx], 1);
        } else {
            atomicAdd(&pA[idx], sAreaP[sidx]);
            atomicAdd(&pR[idx], sRP[sidx]);
            atomicAdd(&pC[idx], sCP[sidx]);
            if (sOvP[sidx]) atomicOr(&ovP[idx], 1);
        }
    }
}

// per-image: nearest gt centroid per pred region, region errors;
// then scatter per-cid values to per-slot tables (fused post-pass).
__global__ void k_match(const int* __restrict__ pA, const int* __restrict__ pR, const int* __restrict__ pC,
                        const int* __restrict__ gA, const int* __restrict__ gR, const int* __restrict__ gC,
                        const int* __restrict__ ovP, const int* __restrict__ ovG,
                        const int* __restrict__ ccntP, const int* __restrict__ ccntG,
                        const int* __restrict__ candCntP, const int* __restrict__ candCntG,
                        const int* __restrict__ slotCidP, const int* __restrict__ slotCidG,
                        float* __restrict__ vPs, float* __restrict__ vGs) {
    __shared__ float sA[KC], sR[KC], sC[KC];
    __shared__ float sEG[KC];
    __shared__ float sFPl[KC], sFGl[KC];
    int b = blockIdx.x;
    int t = threadIdx.x;                           // block = 512 = KC
    int ccg = ccntG[b], ccp = ccntP[b];
    {
        int a = gA[b * KC + t];
        float fa = (float)a;
        float d = fmaxf(fa, 1.0f);
        sA[t] = fa;
        sR[t] = (float)gR[b * KC + t] / d;
        sC[t] = (float)gC[b * KC + t] / d;
        sEG[t] = 0.0f;
    }
    __syncthreads();
    float e_eff = 0.0f;
    int nn = 0;
    if (t < ccp) {
        float pa = (float)pA[b * KC + t];
        float dd = fmaxf(pa, 1.0f);
        float pcr = (float)pR[b * KC + t] / dd;
        float pcc = (float)pC[b * KC + t] / dd;
        float best = INFINITY;
        for (int gi = 0; gi < ccg; gi++) {
            float dr = pcr - sR[gi], dc = pcc - sC[gi];
            float d2 = dr * dr + dc * dc;
            if (d2 < best) { best = d2; nn = gi; }  // first-min ties like argmin
        }
        if (ccg > 0 && ovP[b * KC + t]) {
            float ratio = 1.0f - sA[nn] / dd;
            e_eff = fminf(fabsf(1.0f - expf(ratio)), 1.0f);
        }
    }
    if (e_eff > 0.0f) atomicMax((int*)&sEG[nn], __float_as_int(e_eff));
    sFPl[t] = ovP[b * KC + t] ? e_eff : -1.0f;
    __syncthreads();
    sFGl[t] = ovG[b * KC + t] ? fmaxf(sEG[t], 0.0f) : -1.0f;
    __syncthreads();
    int nP = min(candCntP[b], CCAP), nG = min(candCntG[b], CCAP);
    for (int s2 = t; s2 < nP; s2 += KC) {
        int cid = slotCidP[b * CCAP + s2];
        vPs[b * CCAP + s2] = (cid >= 0) ? sFPl[cid] : -3.0f;   // -3 = fg w/o compact id
    }
    for (int s2 = t; s2 < nG; s2 += KC) {
        int cid = slotCidG[b * CCAP + s2];
        vGs[b * CCAP + s2] = (cid >= 0) ? sFGl[cid] : 0.0f;
    }
}

// per-pixel error rules + fused loss/metric reduction: pure table lookups
__global__ __launch_bounds__(TPB) void k_final(const float* __restrict__ in,
                        const int* __restrict__ slotPacked,
                        const float* __restrict__ vPs, const float* __restrict__ vGs,
                        const int* __restrict__ ccntG, double* __restrict__ acc) {
    __shared__ float pLm[4], pPe[4];
    __shared__ int pCnt[4];
    int b = blockIdx.x >> 6;            // 64 blocks per image
    int blk = blockIdx.x & 63;
    bool hasGt = ccntG[b] > 0;
    const float* vP = vPs + b * CCAP;
    const float* vG = vGs + b * CCAP;
    int i0 = (blk << 12) + threadIdx.x;
    float aLm = 0.0f, aPe = 0.0f;
    int aCnt = 0;
    #pragma unroll
    for (int k = 0; k < 16; k++) {
        int g = (b << 18) + i0 + (k << 8);
        int f = slotPacked[g];
        float x = in[g];
        if (!__any(f != 0)) continue;    // whole wave background
        int fp = f & 0xffff;
        int fg = (f >> 16) & 0xffff;
        float pe = 0.0f;
        if (fp) {
            if (!hasGt) pe = 1.0f;
            else {
                float v = vP[fp - 1];
                if (v > -2.5f) {                  // has compact id
                    if (v < 0.0f) pe = 1.0f;      // pred region w/o overlap
                    else if (!fg) pe = v;         // pred px, gt!=1
                }
            }
        }
        if (fg) {
            float vg = vG[fg - 1];
            if (!fp) pe = fmaxf(pe, fmaxf(vg, 0.0f));   // gt px, pred<1
            if (vg < 0.0f) pe = 1.0f;                    // gt region w/o overlap
        }
        if (pe != 0.0f) {
            float score = 1.0f / (1.0f + expf(-x));
            aLm += (1.0f / (1.0f + expf(-(score + 1.0f) * pe)) - 0.5f) * 2.0f;
            aPe += pe;
            aCnt++;
        }
    }
    for (int o = 32; o; o >>= 1) {
        aLm += __shfl_xor(aLm, o);
        aPe += __shfl_xor(aPe, o);
        aCnt += __shfl_xor(aCnt, o);
    }
    int wv = threadIdx.x >> 6, lane = threadIdx.x & 63;
    if (lane == 0) { pLm[wv] = aLm; pPe[wv] = aPe; pCnt[wv] = aCnt; }
    __syncthreads();
    if (threadIdx.x == 0) {
        double sl = 0, sp = 0; int sc = 0;
        for (int q = 0; q < 4; q++) { sl += pLm[q]; sp += pPe[q]; sc += pCnt[q]; }
        atomicAdd(&acc[0], sl);
        atomicAdd(&acc[1], sp);
        atomicAdd(&acc[2], (double)sc);
    }
}

__global__ void k_out(const double* __restrict__ acc, float* __restrict__ out) {
    out[0] = (float)(acc[0] / (double)PN);
    out[1] = (float)(1.0 - acc[1] / (double)PN);
    out[2] = (float)(1.0 - acc[1] / acc[2]);
}

extern "C" void kernel_launch(void* const* d_in, const int* in_sizes, int n_in,
                              void* d_out, int out_size, void* d_ws, size_t ws_size,
                              hipStream_t stream) {
    const float* in = (const float*)d_in[0];
    const float* tg = (const float*)d_in[1];
    // d_in[2] = epoch, unused by forward

    char* w = (char*)d_ws;
    size_t off = 0;
    int* labP = (int*)(w + off); off += (size_t)PN * 4;
    int* labG = (int*)(w + off); off += (size_t)PN * 4;
    int* slotPacked = (int*)(w + off); off += (size_t)PN * 4;
    int* candP = (int*)(w + off); off += (size_t)NB * CCAP * 4;
    int* candG = (int*)(w + off); off += (size_t)NB * CCAP * 4;
    int* slotCidP = (int*)(w + off); off += (size_t)NB * CCAP * 4;
    int* slotCidG = (int*)(w + off); off += (size_t)NB * CCAP * 4;
    float* vPs = (float*)(w + off); off += (size_t)NB * CCAP * 4;
    float* vGs = (float*)(w + off); off += (size_t)NB * CCAP * 4;
    int* compP = (int*)(w + off); off += (size_t)NB * KC * 4;
    int* compG = (int*)(w + off); off += (size_t)NB * KC * 4;
    size_t zoff = off;
    int* candCntP = (int*)(w + off); off += NB * 4;
    int* candCntG = (int*)(w + off); off += NB * 4;
    int* ccntP = (int*)(w + off); off += NB * 4;
    int* ccntG = (int*)(w + off); off += NB * 4;
    int* sAreaP = (int*)(w + off); off += (size_t)NB * CCAP * 4;
    int* sRP    = (int*)(w + off); off += (size_t)NB * CCAP * 4;
    int* sCP    = (int*)(w + off); off += (size_t)NB * CCAP * 4;
    int* sOvP   = (int*)(w + off); off += (size_t)NB * CCAP * 4;
    int* sAreaG = (int*)(w + off); off += (size_t)NB * CCAP * 4;
    int* sRG    = (int*)(w + off); off += (size_t)NB * CCAP * 4;
    int* sCG    = (int*)(w + off); off += (size_t)NB * CCAP * 4;
    int* sOvG   = (int*)(w + off); off += (size_t)NB * CCAP * 4;
    int* pA = (int*)(w + off); off += (size_t)NB * KC * 4;
    int* pR = (int*)(w + off); off += (size_t)NB * KC * 4;
    int* pC = (int*)(w + off); off += (size_t)NB * KC * 4;
    int* gA = (int*)(w + off); off += (size_t)NB * KC * 4;
    int* gR = (int*)(w + off); off += (size_t)NB * KC * 4;
    int* gC = (int*)(w + off); off += (size_t)NB * KC * 4;
    int* ovP = (int*)(w + off); off += (size_t)NB * KC * 4;
    int* ovG = (int*)(w + off); off += (size_t)NB * KC * 4;
    double* acc = (double*)(w + off); off += 4 * 8;
    size_t zend = off;

    // zero counters, slot stats, cid stats, accumulators (fresh every call)
    hipMemsetAsync(w + zoff, 0, zend - zoff, stream);

    k_local<<<NB * 64, TPB, 0, stream>>>(in, tg, labP, labG, slotPacked,
                                         candP, candG, candCntP, candCntG,
                                         sAreaP, sRP, sCP, sOvP,
                                         sAreaG, sRG, sCG, sOvG);
    {
        const int total = NB * 21 * 512;
        k_bmerge<<<(total + TPB - 1) / TPB, TPB, 0, stream>>>(labP, labG);
    }
    k_sortroots<<<2 * NB, TPB, 0, stream>>>(labP, labG, candP, candG, candCntP, candCntG,
                                            compP, compG, ccntP, ccntG);
    k_redux<<<NB * 2 * (CCAP / TPB), TPB, 0, stream>>>(labP, labG, candP, candG,
                                                       candCntP, candCntG, compP, compG,
                                                       sAreaP, sRP, sCP, sOvP,
                                                       sAreaG, sRG, sCG, sOvG,
                                                       pA, pR, pC, ovP, gA, gR, gC, ovG,
                                                       slotCidP, slotCidG);
    k_match<<<NB, KC, 0, stream>>>(pA, pR, pC, gA, gR, gC, ovP, ovG, ccntP, ccntG,
                                   candCntP, candCntG, slotCidP, slotCidG, vPs, vGs);
    k_final<<<NB * 64, TPB, 0, stream>>>(in, slotPacked, vPs, vGs, ccntG, acc);
    k_out<<<1, 1, 0, stream>>>(acc, (float*)d_out);
}